// Round 9
// baseline (1342.588 us; speedup 1.0000x reference)
//
#include <hip/hip_runtime.h>

#define N_NODES 50000
#define D_FEAT 128
#define N_EDGES 1600000
#define NUM_ITERS 20
#define ZERO_NODE N_NODES          // pad entries gather from this zeroed row
#define HNB 128                    // col-histogram blocks per half
#define HALF_NODES 25000           // nodes per col-histogram half
#define NB 196                     // buckets (row >> 8)
#define BCAP 192                   // per-block per-bucket capacity (mean 64)
#define ABLK 128                   // phase-A blocks
#define PAD 4                      // per-row padding multiple
#define STAGE_CAP 12544            // >= max bucket edges + pad
#define CSR_MAX (N_EDGES + PAD * N_NODES)

#define SLICES 8                   // feature slices (XCD-pinned via bid&7)
#define SFEAT 16                   // features per slice (32B granule)
#define NPB 32                     // nodes per prop block (4 waves x 8)
#define CSR_LDS_CAP 4096           // per-block CSR stage (u16)

typedef unsigned int u32;
typedef unsigned short u16;
typedef unsigned long long u64;

#define SLICE_ELEMS ((size_t)(N_NODES + 1) * SFEAT)   // incl zero row

__device__ __forceinline__ u16 bf16_rne(float f) {
    u32 u = __float_as_uint(f);
    u32 r = u + 0x7fffu + ((u >> 16) & 1u);
    return (u16)(r >> 16);
}

// ---------------- mask dtype detection ---------------------------------------
__global__ void detect_kernel(const u32* __restrict__ w, int nwords,
                              u32* __restrict__ flags) {
    int i = blockIdx.x * blockDim.x + threadIdx.x;
    int stride = gridDim.x * blockDim.x;
    u32 f = 0;
    for (; i < nwords; i += stride) {
        u32 v = w[i];
        if (v > 1u) f |= 1u;
        if (v == 0x3f800000u) f |= 2u;
    }
    if (f) atomicOr(flags, f);
}

// ---------------- col histogram: 256 blocks, blockIdx>>7 selects half --------
__global__ void __launch_bounds__(256) hist_kernel(const int* __restrict__ idx,
                                                   u32* __restrict__ partial, int n) {
    __shared__ u32 h[HALF_NODES / 2];
    for (int i = threadIdx.x; i < HALF_NODES / 2; i += 256) h[i] = 0;
    __syncthreads();
    const int half = blockIdx.x >> 7;
    const int bid = blockIdx.x & (HNB - 1);
    const int base_node = half * HALF_NODES;
    int i = bid * 256 + threadIdx.x;
    const int stride = HNB * 256;
    for (; i < n; i += stride) {
        u32 r = (u32)(idx[i] - base_node);
        if (r < (u32)HALF_NODES) atomicAdd(&h[r >> 1], 1u << ((r & 1) * 16));
    }
    __syncthreads();
    u32* dst = partial + (size_t)bid * (N_NODES / 2) + half * (HALF_NODES / 2);
    for (int j = threadIdx.x; j < HALF_NODES / 2; j += 256) dst[j] = h[j];
}

// ---------------- reduce col partials -> dis ---------------------------------
__global__ void reduce_dis_kernel(const u32* __restrict__ pA, float* __restrict__ dis) {
    int i = blockIdx.x * blockDim.x + threadIdx.x;
    if (i >= N_NODES / 2) return;
    u32 sa = 0;
    for (int b = 0; b < HNB; ++b) sa += pA[(size_t)b * (N_NODES / 2) + i];
    int d0 = (int)(sa & 0xffffu), d1 = (int)(sa >> 16);
    dis[2 * i]     = d0 ? rsqrtf((float)d0) : 0.0f;
    dis[2 * i + 1] = d1 ? rsqrtf((float)d1) : 0.0f;
}

// ---------------- Phase A: per-block bucket scatter (no cross-block races) ---
__global__ void __launch_bounds__(256) bucketA_kernel(const int* __restrict__ row,
                                                      const int* __restrict__ col,
                                                      u32* __restrict__ bucket,
                                                      int* __restrict__ bcnt) {
    __shared__ u32 cur[NB];
    for (int i = threadIdx.x; i < NB; i += 256) cur[i] = 0;
    __syncthreads();
    u32* myreg = bucket + (size_t)blockIdx.x * NB * BCAP;
    int i = blockIdx.x * 256 + threadIdx.x;
    int stride = gridDim.x * 256;
    for (; i < N_EDGES; i += stride) {
        int r = row[i];
        int b = r >> 8;
        u32 pos = atomicAdd(&cur[b], 1u);
        if (pos < (u32)BCAP)
            myreg[(size_t)b * BCAP + pos] = ((u32)(r & 255) << 16) | (u32)col[i];
    }
    __syncthreads();
    for (int i2 = threadIdx.x; i2 < NB; i2 += 256)
        bcnt[blockIdx.x * NB + i2] = (int)min(cur[i2], (u32)BCAP);
}

// ---------------- Phase B1: per-bucket row counts -> padded cnt_p ------------
__global__ void __launch_bounds__(256) b1_kernel(const u32* __restrict__ bucket,
                                                 const int* __restrict__ bcnt,
                                                 int* __restrict__ cnt_p) {
    const int b = blockIdx.x;
    const int tid = threadIdx.x;
    __shared__ int pfx[ABLK + 1];
    __shared__ int cnts[ABLK];
    __shared__ u32 hist[256];
    if (tid < 256) hist[tid] = 0;
    if (tid < ABLK) cnts[tid] = bcnt[tid * NB + b];
    __syncthreads();
    if (tid == 0) {
        int s = 0;
        for (int k = 0; k < ABLK; ++k) { pfx[k] = s; s += cnts[k]; }
        pfx[ABLK] = s;
    }
    __syncthreads();
    const int total = pfx[ABLK];
    for (int t = tid; t < total; t += 256) {
        int lo = 0, hi = ABLK;
        while (hi - lo > 1) { int mid = (lo + hi) >> 1; if (pfx[mid] <= t) lo = mid; else hi = mid; }
        u32 e = bucket[(size_t)lo * NB * BCAP + (size_t)b * BCAP + (t - pfx[lo])];
        atomicAdd(&hist[e >> 16], 1u);
    }
    __syncthreads();
    const int r0 = b << 8;
    if (tid < 256) {
        int r = r0 + tid;
        if (r < N_NODES) cnt_p[r] = ((int)hist[tid] + (PAD - 1)) & ~(PAD - 1);
    }
}

// ---------------- single-block scan over padded counts -----------------------
__global__ void __launch_bounds__(1024) scan_kernel(const int* __restrict__ cnt,
                                                    int* __restrict__ offsets, int n) {
    __shared__ int wsum[16];
    __shared__ int s_carry;
    const int tid = threadIdx.x;
    const int lane = tid & 63, wid = tid >> 6;
    if (tid == 0) s_carry = 0;
    __syncthreads();
    for (int base = 0; base < n; base += 4096) {
        int i4 = base + tid * 4;
        int4 v = make_int4(0, 0, 0, 0);
        if (i4 < n) v = *(const int4*)(cnt + i4);
        int e1 = v.x, e2 = v.x + v.y, e3 = e2 + v.z, tot = e3 + v.w;
        int winc = tot;
        #pragma unroll
        for (int off = 1; off < 64; off <<= 1) {
            int t = __shfl_up(winc, off);
            if (lane >= off) winc += t;
        }
        if (lane == 63) wsum[wid] = winc;
        __syncthreads();
        if (tid < 16) {
            int s = wsum[tid];
            #pragma unroll
            for (int off = 1; off < 16; off <<= 1) {
                int t = __shfl_up(s, off);
                if (tid >= off) s += t;
            }
            wsum[tid] = s;
        }
        __syncthreads();
        int bb = s_carry + (wid ? wsum[wid - 1] : 0) + winc - tot;
        if (i4 < n) *(int4*)(offsets + i4) = make_int4(bb, bb + e1, bb + e2, bb + e3);
        __syncthreads();
        if (tid == 0) s_carry += wsum[15];
        __syncthreads();
    }
    if (tid == 0) offsets[n] = s_carry;
}

// ---------------- Phase B2: build CSR segment for one bucket -----------------
__global__ void __launch_bounds__(256) b2_kernel(const u32* __restrict__ bucket,
                                                 const int* __restrict__ bcnt,
                                                 const int* __restrict__ offsets,
                                                 u16* __restrict__ csr) {
    const int b = blockIdx.x;
    const int tid = threadIdx.x;
    const int r0 = b << 8;
    const int rcount = min(256, N_NODES - r0);
    __shared__ int pfx[ABLK + 1];
    __shared__ int cnts[ABLK];
    __shared__ int lbase[257];
    __shared__ u32 lcur[256];
    __shared__ __align__(16) u16 stage[STAGE_CAP];
    if (tid < ABLK) cnts[tid] = bcnt[tid * NB + b];
    for (int j = tid; j <= rcount; j += 256) lbase[j] = offsets[r0 + j] - offsets[r0];
    if (tid < 256) lcur[tid] = 0;
    __syncthreads();
    if (tid == 0) {
        int s = 0;
        for (int k = 0; k < ABLK; ++k) { pfx[k] = s; s += cnts[k]; }
        pfx[ABLK] = s;
    }
    __syncthreads();
    const int total = pfx[ABLK];
    const int L = min(lbase[rcount], STAGE_CAP);
    for (int j = tid; j < L; j += 256) stage[j] = (u16)ZERO_NODE;
    __syncthreads();
    for (int t = tid; t < total; t += 256) {
        int lo = 0, hi = ABLK;
        while (hi - lo > 1) { int mid = (lo + hi) >> 1; if (pfx[mid] <= t) lo = mid; else hi = mid; }
        u32 e = bucket[(size_t)lo * NB * BCAP + (size_t)b * BCAP + (t - pfx[lo])];
        int lr = (int)(e >> 16);
        u32 p = atomicAdd(&lcur[lr], 1u);
        int idx = lbase[lr] + (int)p;
        if (idx < STAGE_CAP) stage[idx] = (u16)(e & 0xffffu);
    }
    __syncthreads();
    uint4* dst = (uint4*)(csr + offsets[r0]);
    const uint4* src = (const uint4*)stage;
    for (int j = tid; j < (L >> 3); j += 256) dst[j] = src[j];
    if (tid == 0 && (L & 7)) {
        uint2* d2 = (uint2*)(csr + offsets[r0] + (L & ~7));
        const uint2* s2 = (const uint2*)(stage + (L & ~7));
        *d2 = *s2;
    }
}

// ---------------- build: slice-major mask bits + sxm = bf16(dis * masked x) --
__global__ void build_kernel(const void* __restrict__ mask,
                             const u32* __restrict__ flags,
                             const float* __restrict__ x,
                             const float* __restrict__ dis,
                             u32* __restrict__ bits_s,   // [4][N_NODES] (32-feat words)
                             u16* __restrict__ sxm_s,    // [8][N_NODES+1][16]
                             int n) {
    int i = blockIdx.x * blockDim.x + threadIdx.x;
    if (i >= n) return;
    u32 fl = *flags;
    int mv;
    if ((fl & 1u) == 0u) {
        mv = ((const int*)mask)[i];
    } else if (fl & 2u) {
        mv = (((const float*)mask)[i] != 0.0f) ? 1 : 0;
    } else {
        mv = ((const unsigned char*)mask)[i];
    }
    bool pred = (mv != 0);
    u64 b = __ballot(pred);
    int lane = threadIdx.x & 63;
    int wIdx = i >> 5;  // global 32-feat word index = node*4 + blk
    if (lane == 0)  bits_s[(size_t)(wIdx & 3) * N_NODES + (wIdx >> 2)] = (u32)b;
    if (lane == 32) bits_s[(size_t)(wIdx & 3) * N_NODES + (wIdx >> 2)] = (u32)(b >> 32);
    const int node = i >> 7, f = i & 127;
    const int sl = f >> 4, wi = f & 15;
    sxm_s[(size_t)sl * SLICE_ELEMS + (size_t)node * SFEAT + wi] =
        pred ? bf16_rne(dis[node] * x[i]) : (u16)0;
}

// ---------------- zero the gatherable pad rows (slice-major) -----------------
__global__ void zero_rows_kernel(u16* __restrict__ a, u16* __restrict__ b,
                                 u16* __restrict__ c) {
    int t = threadIdx.x;
    if (t < SLICES * SFEAT) {
        int s = t >> 4, e = t & 15;
        size_t g = (size_t)s * SLICE_ELEMS + (size_t)N_NODES * SFEAT + e;
        a[g] = 0; b[g] = 0; c[g] = 0;
    }
}

// ---------------- one propagation step (XCD-pinned feature slice) ------------
// slice = blockIdx & 7 (round-robin -> XCD k sees only slice k: state slice
// is L2-resident). Wave: nd(8 nodes) x fl(2 x 8feats) x eg(4 edges).
template <bool FINAL>
__global__ void __launch_bounds__(256) prop_kernel(const int* __restrict__ offsets,
                                                   const u16* __restrict__ csr,
                                                   const u16* __restrict__ cur,    // slice-major
                                                   const u32* __restrict__ bits_s, // [4][N_NODES]
                                                   const float* __restrict__ dis,
                                                   const u16* __restrict__ sxm_s,  // slice-major
                                                   const float* __restrict__ x,    // node-major f32
                                                   void* __restrict__ nxtp) {
    const int bid = blockIdx.x;
    const int slice = bid & (SLICES - 1);
    const int chunk = bid >> 3;
    const int n0 = chunk * NPB;
    const int tid = threadIdx.x;

    __shared__ int soff[NPB + 1];
    __shared__ __align__(8) u16 csr_lds[CSR_LDS_CAP];

    if (tid <= NPB) soff[tid] = offsets[min(n0 + tid, N_NODES)];
    __syncthreads();
    const int s0 = soff[0];
    const int span = min(soff[NPB] - s0, CSR_LDS_CAP);
    {
        const uint2* gsrc = (const uint2*)(csr + s0);
        uint2* ldst = (uint2*)csr_lds;
        for (int j = tid; j * 4 < span; j += 256) ldst[j] = gsrc[j];
    }
    __syncthreads();

    const int wid = tid >> 6, lane = tid & 63;
    const int nd = lane >> 3;          // 0..7
    const int fl = (lane >> 2) & 1;    // 0..1
    const int eg = lane & 3;           // 0..3
    const int node = n0 + wid * 8 + nd;

    const u16* curs = cur + (size_t)slice * SLICE_ELEMS;
    const int li = wid * 8 + nd;
    const int sl = soff[li] - s0, el = soff[li + 1] - s0;

    float a0 = 0, a1 = 0, a2 = 0, a3 = 0, a4 = 0, a5 = 0, a6 = 0, a7 = 0;
    #pragma unroll 4
    for (int b = sl; b < el; b += 4) {
        const int c = (int)csr_lds[b + eg];
        const uint4 r = *((const uint4*)(curs + (size_t)c * SFEAT) + fl);
        a0 += __uint_as_float(r.x << 16);
        a1 += __uint_as_float(r.x & 0xffff0000u);
        a2 += __uint_as_float(r.y << 16);
        a3 += __uint_as_float(r.y & 0xffff0000u);
        a4 += __uint_as_float(r.z << 16);
        a5 += __uint_as_float(r.z & 0xffff0000u);
        a6 += __uint_as_float(r.w << 16);
        a7 += __uint_as_float(r.w & 0xffff0000u);
    }
    // reduce over eg (lane bits 0..1)
    a0 += __shfl_xor(a0, 1); a0 += __shfl_xor(a0, 2);
    a1 += __shfl_xor(a1, 1); a1 += __shfl_xor(a1, 2);
    a2 += __shfl_xor(a2, 1); a2 += __shfl_xor(a2, 2);
    a3 += __shfl_xor(a3, 1); a3 += __shfl_xor(a3, 2);
    a4 += __shfl_xor(a4, 1); a4 += __shfl_xor(a4, 2);
    a5 += __shfl_xor(a5, 1); a5 += __shfl_xor(a5, 2);
    a6 += __shfl_xor(a6, 1); a6 += __shfl_xor(a6, 2);
    a7 += __shfl_xor(a7, 1); a7 += __shfl_xor(a7, 2);

    if (eg == 0 && node < N_NODES) {
        const u32 w = bits_s[(size_t)(slice >> 1) * N_NODES + node];
        const u32 mb = (w >> (((slice & 1) << 4) + (fl << 3))) & 0xffu;
        const float dr = dis[node];
        if (FINAL) {
            const int fb = node * D_FEAT + slice * SFEAT + fl * 8;
            const float4 x0 = *(const float4*)(x + fb);
            const float4 x1 = *(const float4*)(x + fb + 4);
            float* outp = (float*)nxtp;
            float4 o0, o1;
            o0.x = (mb & 0x01u) ? x0.x : dr * a0;
            o0.y = (mb & 0x02u) ? x0.y : dr * a1;
            o0.z = (mb & 0x04u) ? x0.z : dr * a2;
            o0.w = (mb & 0x08u) ? x0.w : dr * a3;
            o1.x = (mb & 0x10u) ? x1.x : dr * a4;
            o1.y = (mb & 0x20u) ? x1.y : dr * a5;
            o1.z = (mb & 0x40u) ? x1.z : dr * a6;
            o1.w = (mb & 0x80u) ? x1.w : dr * a7;
            *(float4*)(outp + fb) = o0;
            *(float4*)(outp + fb + 4) = o1;
        } else {
            const float d2 = dr * dr;
            const size_t g = (size_t)slice * SLICE_ELEMS + (size_t)node * SFEAT + fl * 8;
            const uint4 sv = *(const uint4*)(sxm_s + g);
            u16 t0 = (mb & 0x01u) ? (u16)(sv.x)       : bf16_rne(d2 * a0);
            u16 t1 = (mb & 0x02u) ? (u16)(sv.x >> 16) : bf16_rne(d2 * a1);
            u16 t2 = (mb & 0x04u) ? (u16)(sv.y)       : bf16_rne(d2 * a2);
            u16 t3 = (mb & 0x08u) ? (u16)(sv.y >> 16) : bf16_rne(d2 * a3);
            u16 t4 = (mb & 0x10u) ? (u16)(sv.z)       : bf16_rne(d2 * a4);
            u16 t5 = (mb & 0x20u) ? (u16)(sv.z >> 16) : bf16_rne(d2 * a5);
            u16 t6 = (mb & 0x40u) ? (u16)(sv.w)       : bf16_rne(d2 * a6);
            u16 t7 = (mb & 0x80u) ? (u16)(sv.w >> 16) : bf16_rne(d2 * a7);
            uint4 st;
            st.x = (u32)t0 | ((u32)t1 << 16);
            st.y = (u32)t2 | ((u32)t3 << 16);
            st.z = (u32)t4 | ((u32)t5 << 16);
            st.w = (u32)t6 | ((u32)t7 << 16);
            *(uint4*)(((u16*)nxtp) + g) = st;
        }
    }
}

extern "C" void kernel_launch(void* const* d_in, const int* in_sizes, int n_in,
                              void* d_out, int out_size, void* d_ws, size_t ws_size,
                              hipStream_t stream) {
    const float* x = (const float*)d_in[0];
    const int* edge = (const int*)d_in[1];
    const void* mask = d_in[2];
    const int* row = edge;             // edge_index[0]
    const int* col = edge + N_EDGES;   // edge_index[1]
    float* out = (float*)d_out;

    char* ws = (char*)d_ws;
    size_t off = 0;
    auto alloc = [&](size_t bytes) -> void* {
        void* p = ws + off;
        off += (bytes + 255) & ~(size_t)255;
        return p;
    };
    int*   offsets = (int*)alloc((size_t)(N_NODES + 1) * 4);
    int*   cnt_p   = (int*)alloc((size_t)N_NODES * 4);
    float* dis     = (float*)alloc((size_t)N_NODES * 4);
    u32*   flags   = (u32*)alloc(256);
    u32*   bits_s  = (u32*)alloc((size_t)4 * N_NODES * 4);            // 0.8 MB
    u32*   pA      = (u32*)alloc((size_t)HNB * (N_NODES / 2) * 4);    // 12.8 MB
    u32*   bucket  = (u32*)alloc((size_t)ABLK * NB * BCAP * 4);       // 19.3 MB
    int*   bcnt    = (int*)alloc((size_t)ABLK * NB * 4);
    u16*   csr     = (u16*)alloc((size_t)CSR_MAX * 2);
    u16*   sxm_s   = (u16*)alloc((size_t)SLICES * SLICE_ELEMS * 2);   // 12.8 MB
    u16*   stA     = (u16*)alloc((size_t)SLICES * SLICE_ELEMS * 2);
    u16*   stB     = (u16*)alloc((size_t)SLICES * SLICE_ELEMS * 2);

    hipMemsetAsync(flags, 0, 4, stream);

    const int total_feat = N_NODES * D_FEAT;
    const int mask_words = total_feat / 4;

    detect_kernel<<<1024, 256, 0, stream>>>((const u32*)mask, mask_words, flags);
    hist_kernel<<<2 * HNB, 256, 0, stream>>>(col, pA, N_EDGES);
    reduce_dis_kernel<<<(N_NODES / 2 + 255) / 256, 256, 0, stream>>>(pA, dis);
    bucketA_kernel<<<ABLK, 256, 0, stream>>>(row, col, bucket, bcnt);
    b1_kernel<<<NB, 256, 0, stream>>>(bucket, bcnt, cnt_p);
    scan_kernel<<<1, 1024, 0, stream>>>(cnt_p, offsets, N_NODES);
    build_kernel<<<total_feat / 256, 256, 0, stream>>>(mask, flags, x, dis, bits_s, sxm_s, total_feat);
    b2_kernel<<<NB, 256, 0, stream>>>(bucket, bcnt, offsets, csr);
    zero_rows_kernel<<<1, 256, 0, stream>>>(sxm_s, stA, stB);

    const int chunks = (N_NODES + NPB - 1) / NPB;   // 1563
    const int prop_blocks = SLICES * chunks;        // 12504
    const u16* src = sxm_s;  // s0 = dis * (mask ? x : 0) == sxm exactly
    for (int it = 0; it < NUM_ITERS; ++it) {
        if (it < NUM_ITERS - 1) {
            u16* dst = (it & 1) ? stB : stA;
            prop_kernel<false><<<prop_blocks, 256, 0, stream>>>(offsets, csr, src, bits_s, dis, sxm_s, x, dst);
            src = dst;
        } else {
            prop_kernel<true><<<prop_blocks, 256, 0, stream>>>(offsets, csr, src, bits_s, dis, sxm_s, x, out);
        }
    }
}

// Round 11
// 1175.492 us; speedup vs baseline: 1.1421x; 1.1421x over previous
//
#include <hip/hip_runtime.h>

#define N_NODES 50000
#define D_FEAT 128
#define N_EDGES 1600000
#define NUM_ITERS 20
#define ZERO_NODE N_NODES          // pad entries gather from this zeroed row
#define HNB 128                    // col-histogram blocks per half
#define HALF_NODES 25000           // nodes per col-histogram half
#define NB 196                     // buckets (row >> 8)
#define BCAP 192                   // per-block per-bucket capacity (mean 64)
#define ABLK 128                   // phase-A blocks
#define PAD 4                      // per-row padding multiple
#define STAGE_CAP 12544            // >= max bucket edges + pad
#define CSR_MAX (N_EDGES + PAD * N_NODES)

typedef unsigned int u32;
typedef unsigned short u16;
typedef unsigned long long u64;
typedef u32 u32x4 __attribute__((ext_vector_type(4)));
typedef float f32x4 __attribute__((ext_vector_type(4)));

__device__ __forceinline__ u16 bf16_rne(float f) {
    u32 u = __float_as_uint(f);
    u32 r = u + 0x7fffu + ((u >> 16) & 1u);
    return (u16)(r >> 16);
}

// ---------------- mask dtype detection ---------------------------------------
__global__ void detect_kernel(const u32* __restrict__ w, int nwords,
                              u32* __restrict__ flags) {
    int i = blockIdx.x * blockDim.x + threadIdx.x;
    int stride = gridDim.x * blockDim.x;
    u32 f = 0;
    for (; i < nwords; i += stride) {
        u32 v = w[i];
        if (v > 1u) f |= 1u;
        if (v == 0x3f800000u) f |= 2u;
    }
    if (f) atomicOr(flags, f);
}

// ---------------- col histogram: 256 blocks, blockIdx>>7 selects half --------
__global__ void __launch_bounds__(256) hist_kernel(const int* __restrict__ idx,
                                                   u32* __restrict__ partial, int n) {
    __shared__ u32 h[HALF_NODES / 2];
    for (int i = threadIdx.x; i < HALF_NODES / 2; i += 256) h[i] = 0;
    __syncthreads();
    const int half = blockIdx.x >> 7;
    const int bid = blockIdx.x & (HNB - 1);
    const int base_node = half * HALF_NODES;
    int i = bid * 256 + threadIdx.x;
    const int stride = HNB * 256;
    for (; i < n; i += stride) {
        u32 r = (u32)(idx[i] - base_node);
        if (r < (u32)HALF_NODES) atomicAdd(&h[r >> 1], 1u << ((r & 1) * 16));
    }
    __syncthreads();
    u32* dst = partial + (size_t)bid * (N_NODES / 2) + half * (HALF_NODES / 2);
    for (int j = threadIdx.x; j < HALF_NODES / 2; j += 256) dst[j] = h[j];
}

// ---------------- reduce col partials -> dis ---------------------------------
__global__ void reduce_dis_kernel(const u32* __restrict__ pA, float* __restrict__ dis) {
    int i = blockIdx.x * blockDim.x + threadIdx.x;
    if (i >= N_NODES / 2) return;
    u32 sa = 0;
    for (int b = 0; b < HNB; ++b) sa += pA[(size_t)b * (N_NODES / 2) + i];
    int d0 = (int)(sa & 0xffffu), d1 = (int)(sa >> 16);
    dis[2 * i]     = d0 ? rsqrtf((float)d0) : 0.0f;
    dis[2 * i + 1] = d1 ? rsqrtf((float)d1) : 0.0f;
}

// ---------------- Phase A: per-block bucket scatter (no cross-block races) ---
__global__ void __launch_bounds__(256) bucketA_kernel(const int* __restrict__ row,
                                                      const int* __restrict__ col,
                                                      u32* __restrict__ bucket,
                                                      int* __restrict__ bcnt) {
    __shared__ u32 cur[NB];
    for (int i = threadIdx.x; i < NB; i += 256) cur[i] = 0;
    __syncthreads();
    u32* myreg = bucket + (size_t)blockIdx.x * NB * BCAP;
    int i = blockIdx.x * 256 + threadIdx.x;
    int stride = gridDim.x * 256;
    for (; i < N_EDGES; i += stride) {
        int r = row[i];
        int b = r >> 8;
        u32 pos = atomicAdd(&cur[b], 1u);
        if (pos < (u32)BCAP)
            myreg[(size_t)b * BCAP + pos] = ((u32)(r & 255) << 16) | (u32)col[i];
    }
    __syncthreads();
    for (int i2 = threadIdx.x; i2 < NB; i2 += 256)
        bcnt[blockIdx.x * NB + i2] = (int)min(cur[i2], (u32)BCAP);
}

// ---------------- Phase B1: per-bucket row counts -> padded cnt_p ------------
__global__ void __launch_bounds__(256) b1_kernel(const u32* __restrict__ bucket,
                                                 const int* __restrict__ bcnt,
                                                 int* __restrict__ cnt_p) {
    const int b = blockIdx.x;
    const int tid = threadIdx.x;
    __shared__ int pfx[ABLK + 1];
    __shared__ int cnts[ABLK];
    __shared__ u32 hist[256];
    if (tid < 256) hist[tid] = 0;
    if (tid < ABLK) cnts[tid] = bcnt[tid * NB + b];
    __syncthreads();
    if (tid == 0) {
        int s = 0;
        for (int k = 0; k < ABLK; ++k) { pfx[k] = s; s += cnts[k]; }
        pfx[ABLK] = s;
    }
    __syncthreads();
    const int total = pfx[ABLK];
    for (int t = tid; t < total; t += 256) {
        int lo = 0, hi = ABLK;
        while (hi - lo > 1) { int mid = (lo + hi) >> 1; if (pfx[mid] <= t) lo = mid; else hi = mid; }
        u32 e = bucket[(size_t)lo * NB * BCAP + (size_t)b * BCAP + (t - pfx[lo])];
        atomicAdd(&hist[e >> 16], 1u);
    }
    __syncthreads();
    const int r0 = b << 8;
    if (tid < 256) {
        int r = r0 + tid;
        if (r < N_NODES) cnt_p[r] = ((int)hist[tid] + (PAD - 1)) & ~(PAD - 1);
    }
}

// ---------------- single-block scan over padded counts -----------------------
__global__ void __launch_bounds__(1024) scan_kernel(const int* __restrict__ cnt,
                                                    int* __restrict__ offsets, int n) {
    __shared__ int wsum[16];
    __shared__ int s_carry;
    const int tid = threadIdx.x;
    const int lane = tid & 63, wid = tid >> 6;
    if (tid == 0) s_carry = 0;
    __syncthreads();
    for (int base = 0; base < n; base += 4096) {
        int i4 = base + tid * 4;
        int4 v = make_int4(0, 0, 0, 0);
        if (i4 < n) v = *(const int4*)(cnt + i4);
        int e1 = v.x, e2 = v.x + v.y, e3 = e2 + v.z, tot = e3 + v.w;
        int winc = tot;
        #pragma unroll
        for (int off = 1; off < 64; off <<= 1) {
            int t = __shfl_up(winc, off);
            if (lane >= off) winc += t;
        }
        if (lane == 63) wsum[wid] = winc;
        __syncthreads();
        if (tid < 16) {
            int s = wsum[tid];
            #pragma unroll
            for (int off = 1; off < 16; off <<= 1) {
                int t = __shfl_up(s, off);
                if (tid >= off) s += t;
            }
            wsum[tid] = s;
        }
        __syncthreads();
        int bb = s_carry + (wid ? wsum[wid - 1] : 0) + winc - tot;
        if (i4 < n) *(int4*)(offsets + i4) = make_int4(bb, bb + e1, bb + e2, bb + e3);
        __syncthreads();
        if (tid == 0) s_carry += wsum[15];
        __syncthreads();
    }
    if (tid == 0) offsets[n] = s_carry;
}

// ---------------- Phase B2: build CSR segment for one bucket -----------------
__global__ void __launch_bounds__(256) b2_kernel(const u32* __restrict__ bucket,
                                                 const int* __restrict__ bcnt,
                                                 const int* __restrict__ offsets,
                                                 u16* __restrict__ csr) {
    const int b = blockIdx.x;
    const int tid = threadIdx.x;
    const int r0 = b << 8;
    const int rcount = min(256, N_NODES - r0);
    __shared__ int pfx[ABLK + 1];
    __shared__ int cnts[ABLK];
    __shared__ int lbase[257];
    __shared__ u32 lcur[256];
    __shared__ __align__(16) u16 stage[STAGE_CAP];
    if (tid < ABLK) cnts[tid] = bcnt[tid * NB + b];
    for (int j = tid; j <= rcount; j += 256) lbase[j] = offsets[r0 + j] - offsets[r0];
    if (tid < 256) lcur[tid] = 0;
    __syncthreads();
    if (tid == 0) {
        int s = 0;
        for (int k = 0; k < ABLK; ++k) { pfx[k] = s; s += cnts[k]; }
        pfx[ABLK] = s;
    }
    __syncthreads();
    const int total = pfx[ABLK];
    const int L = min(lbase[rcount], STAGE_CAP);
    for (int j = tid; j < L; j += 256) stage[j] = (u16)ZERO_NODE;
    __syncthreads();
    for (int t = tid; t < total; t += 256) {
        int lo = 0, hi = ABLK;
        while (hi - lo > 1) { int mid = (lo + hi) >> 1; if (pfx[mid] <= t) lo = mid; else hi = mid; }
        u32 e = bucket[(size_t)lo * NB * BCAP + (size_t)b * BCAP + (t - pfx[lo])];
        int lr = (int)(e >> 16);
        u32 p = atomicAdd(&lcur[lr], 1u);
        int idx = lbase[lr] + (int)p;
        if (idx < STAGE_CAP) stage[idx] = (u16)(e & 0xffffu);
    }
    __syncthreads();
    uint4* dst = (uint4*)(csr + offsets[r0]);
    const uint4* src = (const uint4*)stage;
    for (int j = tid; j < (L >> 3); j += 256) dst[j] = src[j];
    if (tid == 0 && (L & 7)) {
        uint2* d2 = (uint2*)(csr + offsets[r0] + (L & ~7));
        const uint2* s2 = (const uint2*)(stage + (L & ~7));
        *d2 = *s2;
    }
}

// ---------------- build: mask bits + sxm = bf16(dis * masked x) --------------
__global__ void build_kernel(const void* __restrict__ mask,
                             const u32* __restrict__ flags,
                             const float* __restrict__ x,
                             const float* __restrict__ dis,
                             u32* __restrict__ bits,
                             u16* __restrict__ sxm, int n) {
    int i = blockIdx.x * blockDim.x + threadIdx.x;
    if (i >= n) return;
    u32 fl = *flags;
    int mv;
    if ((fl & 1u) == 0u) {
        mv = ((const int*)mask)[i];
    } else if (fl & 2u) {
        mv = (((const float*)mask)[i] != 0.0f) ? 1 : 0;
    } else {
        mv = ((const unsigned char*)mask)[i];
    }
    bool pred = (mv != 0);
    u64 b = __ballot(pred);
    int lane = threadIdx.x & 63;
    if (lane == 0)  bits[i >> 5] = (u32)b;
    if (lane == 32) bits[i >> 5] = (u32)(b >> 32);
    sxm[i] = pred ? bf16_rne(dis[i >> 7] * x[i]) : (u16)0;
}

// ---------------- one propagation step ---------------------------------------
// Branch-free: rows padded to multiple of 4 with ZERO_NODE (zeroed row).
// Streams (csr, sxm, bits, x) use non-temporal loads so the gatherable state
// keeps the L2. Gather loads stay cached.
template <bool FINAL>
__global__ void __launch_bounds__(256) prop_kernel(const int* __restrict__ offsets,
                                                   const u16* __restrict__ csr,
                                                   const u16* __restrict__ cur,
                                                   const u32* __restrict__ bits,
                                                   const float* __restrict__ dis,
                                                   const u16* __restrict__ sxm,
                                                   const float* __restrict__ x,
                                                   void* __restrict__ nxtp) {
    const int tid = threadIdx.x;
    const int wid = tid >> 6, lane = tid & 63;
    const int node = blockIdx.x * 4 + wid;
    if (node >= N_NODES) return;
    const int fl = lane & 15, eg = lane >> 4;
    const int s = offsets[node], e = offsets[node + 1];

    float a0 = 0, a1 = 0, a2 = 0, a3 = 0, a4 = 0, a5 = 0, a6 = 0, a7 = 0;
    #pragma unroll 4
    for (int base = s; base < e; base += 4) {
        const int c = (int)__builtin_nontemporal_load(csr + base + eg);
        const uint4 r = *((const uint4*)(cur + (size_t)c * D_FEAT) + fl);
        a0 += __uint_as_float(r.x << 16);
        a1 += __uint_as_float(r.x & 0xffff0000u);
        a2 += __uint_as_float(r.y << 16);
        a3 += __uint_as_float(r.y & 0xffff0000u);
        a4 += __uint_as_float(r.z << 16);
        a5 += __uint_as_float(r.z & 0xffff0000u);
        a6 += __uint_as_float(r.w << 16);
        a7 += __uint_as_float(r.w & 0xffff0000u);
    }
    a0 += __shfl_xor(a0, 16); a0 += __shfl_xor(a0, 32);
    a1 += __shfl_xor(a1, 16); a1 += __shfl_xor(a1, 32);
    a2 += __shfl_xor(a2, 16); a2 += __shfl_xor(a2, 32);
    a3 += __shfl_xor(a3, 16); a3 += __shfl_xor(a3, 32);
    a4 += __shfl_xor(a4, 16); a4 += __shfl_xor(a4, 32);
    a5 += __shfl_xor(a5, 16); a5 += __shfl_xor(a5, 32);
    a6 += __shfl_xor(a6, 16); a6 += __shfl_xor(a6, 32);
    a7 += __shfl_xor(a7, 16); a7 += __shfl_xor(a7, 32);

    if (eg == 0) {
        const int fbase = node * D_FEAT + fl * 8;
        const u32 w = __builtin_nontemporal_load(bits + node * 4 + (fl >> 2));
        const u32 mb = (w >> ((fl & 3) * 8)) & 0xffu;
        const float dr = dis[node];
        if (FINAL) {
            const f32x4 x0 = __builtin_nontemporal_load((const f32x4*)(x + fbase));
            const f32x4 x1 = __builtin_nontemporal_load((const f32x4*)(x + fbase + 4));
            float* outp = (float*)nxtp;
            f32x4 o0, o1;
            o0.x = (mb & 0x01u) ? x0.x : dr * a0;
            o0.y = (mb & 0x02u) ? x0.y : dr * a1;
            o0.z = (mb & 0x04u) ? x0.z : dr * a2;
            o0.w = (mb & 0x08u) ? x0.w : dr * a3;
            o1.x = (mb & 0x10u) ? x1.x : dr * a4;
            o1.y = (mb & 0x20u) ? x1.y : dr * a5;
            o1.z = (mb & 0x40u) ? x1.z : dr * a6;
            o1.w = (mb & 0x80u) ? x1.w : dr * a7;
            *(f32x4*)(outp + fbase) = o0;
            *(f32x4*)(outp + fbase + 4) = o1;
        } else {
            const float d2 = dr * dr;
            const u32x4 sv = __builtin_nontemporal_load((const u32x4*)(sxm + fbase));
            u16 t0 = (mb & 0x01u) ? (u16)(sv.x)       : bf16_rne(d2 * a0);
            u16 t1 = (mb & 0x02u) ? (u16)(sv.x >> 16) : bf16_rne(d2 * a1);
            u16 t2 = (mb & 0x04u) ? (u16)(sv.y)       : bf16_rne(d2 * a2);
            u16 t3 = (mb & 0x08u) ? (u16)(sv.y >> 16) : bf16_rne(d2 * a3);
            u16 t4 = (mb & 0x10u) ? (u16)(sv.z)       : bf16_rne(d2 * a4);
            u16 t5 = (mb & 0x20u) ? (u16)(sv.z >> 16) : bf16_rne(d2 * a5);
            u16 t6 = (mb & 0x40u) ? (u16)(sv.w)       : bf16_rne(d2 * a6);
            u16 t7 = (mb & 0x80u) ? (u16)(sv.w >> 16) : bf16_rne(d2 * a7);
            u32x4 st;
            st.x = (u32)t0 | ((u32)t1 << 16);
            st.y = (u32)t2 | ((u32)t3 << 16);
            st.z = (u32)t4 | ((u32)t5 << 16);
            st.w = (u32)t6 | ((u32)t7 << 16);
            *(u32x4*)(((u16*)nxtp) + fbase) = st;
        }
    }
}

extern "C" void kernel_launch(void* const* d_in, const int* in_sizes, int n_in,
                              void* d_out, int out_size, void* d_ws, size_t ws_size,
                              hipStream_t stream) {
    const float* x = (const float*)d_in[0];
    const int* edge = (const int*)d_in[1];
    const void* mask = d_in[2];
    const int* row = edge;             // edge_index[0]
    const int* col = edge + N_EDGES;   // edge_index[1]
    float* out = (float*)d_out;

    char* ws = (char*)d_ws;
    size_t off = 0;
    auto alloc = [&](size_t bytes) -> void* {
        void* p = ws + off;
        off += (bytes + 255) & ~(size_t)255;
        return p;
    };
    const size_t state_elems = (size_t)(N_NODES + 1) * D_FEAT;  // +1 zero row
    int*   offsets = (int*)alloc((size_t)(N_NODES + 1) * 4);
    int*   cnt_p   = (int*)alloc((size_t)N_NODES * 4);
    float* dis     = (float*)alloc((size_t)N_NODES * 4);
    u32*   flags   = (u32*)alloc(256);
    u32*   bits    = (u32*)alloc((size_t)N_NODES * D_FEAT / 8);
    u32*   pA      = (u32*)alloc((size_t)HNB * (N_NODES / 2) * 4);    // 12.8 MB
    u32*   bucket  = (u32*)alloc((size_t)ABLK * NB * BCAP * 4);       // 19.3 MB
    int*   bcnt    = (int*)alloc((size_t)ABLK * NB * 4);
    u16*   csr     = (u16*)alloc((size_t)CSR_MAX * 2);
    u16*   sxm     = (u16*)alloc(state_elems * 2);
    u16*   stA     = (u16*)alloc(state_elems * 2);
    u16*   stB     = (u16*)alloc(state_elems * 2);

    (void)hipMemsetAsync(flags, 0, 4, stream);
    (void)hipMemsetAsync(sxm + (size_t)N_NODES * D_FEAT, 0, D_FEAT * 2, stream);
    (void)hipMemsetAsync(stA + (size_t)N_NODES * D_FEAT, 0, D_FEAT * 2, stream);
    (void)hipMemsetAsync(stB + (size_t)N_NODES * D_FEAT, 0, D_FEAT * 2, stream);

    const int total_feat = N_NODES * D_FEAT;
    const int mask_words = total_feat / 4;

    detect_kernel<<<1024, 256, 0, stream>>>((const u32*)mask, mask_words, flags);
    hist_kernel<<<2 * HNB, 256, 0, stream>>>(col, pA, N_EDGES);
    reduce_dis_kernel<<<(N_NODES / 2 + 255) / 256, 256, 0, stream>>>(pA, dis);
    bucketA_kernel<<<ABLK, 256, 0, stream>>>(row, col, bucket, bcnt);
    b1_kernel<<<NB, 256, 0, stream>>>(bucket, bcnt, cnt_p);
    scan_kernel<<<1, 1024, 0, stream>>>(cnt_p, offsets, N_NODES);
    build_kernel<<<total_feat / 256, 256, 0, stream>>>(mask, flags, x, dis, bits, sxm, total_feat);
    b2_kernel<<<NB, 256, 0, stream>>>(bucket, bcnt, offsets, csr);

    const int prop_blocks = (N_NODES + 3) / 4;
    const u16* src = sxm;  // s0 = dis * (mask ? x : 0) == sxm exactly
    for (int it = 0; it < NUM_ITERS; ++it) {
        if (it < NUM_ITERS - 1) {
            u16* dst = (it & 1) ? stB : stA;
            prop_kernel<false><<<prop_blocks, 256, 0, stream>>>(offsets, csr, src, bits, dis, sxm, x, dst);
            src = dst;
        } else {
            prop_kernel<true><<<prop_blocks, 256, 0, stream>>>(offsets, csr, src, bits, dis, sxm, x, out);
        }
    }
}

// Round 12
// 1101.282 us; speedup vs baseline: 1.2191x; 1.0674x over previous
//
#include <hip/hip_runtime.h>

#define N_NODES 50000
#define D_FEAT 128
#define N_EDGES 1600000
#define NUM_ITERS 20
#define ZERO_NODE N_NODES          // pad entries gather from this zeroed row
#define HNB 128                    // col-histogram blocks per half
#define HALF_NODES 25000           // nodes per col-histogram half
#define NB 196                     // buckets (row >> 8)
#define BCAP 192                   // per-block per-bucket capacity (mean 64)
#define ABLK 128                   // phase-A blocks
#define PAD 16                     // per-row padding multiple
#define STAGE_CAP 12800            // >= max bucket edges + pad slack
#define CSR_MAX (N_EDGES + PAD * N_NODES)

typedef unsigned int u32;
typedef unsigned short u16;
typedef unsigned long long u64;

__device__ __forceinline__ u16 bf16_rne(float f) {
    u32 u = __float_as_uint(f);
    u32 r = u + 0x7fffu + ((u >> 16) & 1u);
    return (u16)(r >> 16);
}

// ---------------- mask dtype detection ---------------------------------------
__global__ void detect_kernel(const u32* __restrict__ w, int nwords,
                              u32* __restrict__ flags) {
    int i = blockIdx.x * blockDim.x + threadIdx.x;
    int stride = gridDim.x * blockDim.x;
    u32 f = 0;
    for (; i < nwords; i += stride) {
        u32 v = w[i];
        if (v > 1u) f |= 1u;
        if (v == 0x3f800000u) f |= 2u;
    }
    if (f) atomicOr(flags, f);
}

// ---------------- col histogram: 256 blocks, blockIdx>>7 selects half --------
__global__ void __launch_bounds__(256) hist_kernel(const int* __restrict__ idx,
                                                   u32* __restrict__ partial, int n) {
    __shared__ u32 h[HALF_NODES / 2];
    for (int i = threadIdx.x; i < HALF_NODES / 2; i += 256) h[i] = 0;
    __syncthreads();
    const int half = blockIdx.x >> 7;
    const int bid = blockIdx.x & (HNB - 1);
    const int base_node = half * HALF_NODES;
    int i = bid * 256 + threadIdx.x;
    const int stride = HNB * 256;
    for (; i < n; i += stride) {
        u32 r = (u32)(idx[i] - base_node);
        if (r < (u32)HALF_NODES) atomicAdd(&h[r >> 1], 1u << ((r & 1) * 16));
    }
    __syncthreads();
    u32* dst = partial + (size_t)bid * (N_NODES / 2) + half * (HALF_NODES / 2);
    for (int j = threadIdx.x; j < HALF_NODES / 2; j += 256) dst[j] = h[j];
}

// ---------------- reduce col partials -> dis ---------------------------------
__global__ void reduce_dis_kernel(const u32* __restrict__ pA, float* __restrict__ dis) {
    int i = blockIdx.x * blockDim.x + threadIdx.x;
    if (i >= N_NODES / 2) return;
    u32 sa = 0;
    for (int b = 0; b < HNB; ++b) sa += pA[(size_t)b * (N_NODES / 2) + i];
    int d0 = (int)(sa & 0xffffu), d1 = (int)(sa >> 16);
    dis[2 * i]     = d0 ? rsqrtf((float)d0) : 0.0f;
    dis[2 * i + 1] = d1 ? rsqrtf((float)d1) : 0.0f;
}

// ---------------- Phase A: per-block bucket scatter (no cross-block races) ---
__global__ void __launch_bounds__(256) bucketA_kernel(const int* __restrict__ row,
                                                      const int* __restrict__ col,
                                                      u32* __restrict__ bucket,
                                                      int* __restrict__ bcnt) {
    __shared__ u32 cur[NB];
    for (int i = threadIdx.x; i < NB; i += 256) cur[i] = 0;
    __syncthreads();
    u32* myreg = bucket + (size_t)blockIdx.x * NB * BCAP;
    int i = blockIdx.x * 256 + threadIdx.x;
    int stride = gridDim.x * 256;
    for (; i < N_EDGES; i += stride) {
        int r = row[i];
        int b = r >> 8;
        u32 pos = atomicAdd(&cur[b], 1u);
        if (pos < (u32)BCAP)
            myreg[(size_t)b * BCAP + pos] = ((u32)(r & 255) << 16) | (u32)col[i];
    }
    __syncthreads();
    for (int i2 = threadIdx.x; i2 < NB; i2 += 256)
        bcnt[blockIdx.x * NB + i2] = (int)min(cur[i2], (u32)BCAP);
}

// ---------------- Phase B1: per-bucket row counts -> padded cnt_p ------------
__global__ void __launch_bounds__(256) b1_kernel(const u32* __restrict__ bucket,
                                                 const int* __restrict__ bcnt,
                                                 int* __restrict__ cnt_p) {
    const int b = blockIdx.x;
    const int tid = threadIdx.x;
    __shared__ int pfx[ABLK + 1];
    __shared__ int cnts[ABLK];
    __shared__ u32 hist[256];
    if (tid < 256) hist[tid] = 0;
    if (tid < ABLK) cnts[tid] = bcnt[tid * NB + b];
    __syncthreads();
    if (tid == 0) {
        int s = 0;
        for (int k = 0; k < ABLK; ++k) { pfx[k] = s; s += cnts[k]; }
        pfx[ABLK] = s;
    }
    __syncthreads();
    const int total = pfx[ABLK];
    for (int t = tid; t < total; t += 256) {
        int lo = 0, hi = ABLK;
        while (hi - lo > 1) { int mid = (lo + hi) >> 1; if (pfx[mid] <= t) lo = mid; else hi = mid; }
        u32 e = bucket[(size_t)lo * NB * BCAP + (size_t)b * BCAP + (t - pfx[lo])];
        atomicAdd(&hist[e >> 16], 1u);
    }
    __syncthreads();
    const int r0 = b << 8;
    if (tid < 256) {
        int r = r0 + tid;
        if (r < N_NODES) cnt_p[r] = ((int)hist[tid] + (PAD - 1)) & ~(PAD - 1);
    }
}

// ---------------- single-block scan over padded counts -----------------------
__global__ void __launch_bounds__(1024) scan_kernel(const int* __restrict__ cnt,
                                                    int* __restrict__ offsets, int n) {
    __shared__ int wsum[16];
    __shared__ int s_carry;
    const int tid = threadIdx.x;
    const int lane = tid & 63, wid = tid >> 6;
    if (tid == 0) s_carry = 0;
    __syncthreads();
    for (int base = 0; base < n; base += 4096) {
        int i4 = base + tid * 4;
        int4 v = make_int4(0, 0, 0, 0);
        if (i4 < n) v = *(const int4*)(cnt + i4);
        int e1 = v.x, e2 = v.x + v.y, e3 = e2 + v.z, tot = e3 + v.w;
        int winc = tot;
        #pragma unroll
        for (int off = 1; off < 64; off <<= 1) {
            int t = __shfl_up(winc, off);
            if (lane >= off) winc += t;
        }
        if (lane == 63) wsum[wid] = winc;
        __syncthreads();
        if (tid < 16) {
            int s = wsum[tid];
            #pragma unroll
            for (int off = 1; off < 16; off <<= 1) {
                int t = __shfl_up(s, off);
                if (tid >= off) s += t;
            }
            wsum[tid] = s;
        }
        __syncthreads();
        int bb = s_carry + (wid ? wsum[wid - 1] : 0) + winc - tot;
        if (i4 < n) *(int4*)(offsets + i4) = make_int4(bb, bb + e1, bb + e2, bb + e3);
        __syncthreads();
        if (tid == 0) s_carry += wsum[15];
        __syncthreads();
    }
    if (tid == 0) offsets[n] = s_carry;
}

// ---------------- Phase B2: build CSR segment for one bucket -----------------
__global__ void __launch_bounds__(256) b2_kernel(const u32* __restrict__ bucket,
                                                 const int* __restrict__ bcnt,
                                                 const int* __restrict__ offsets,
                                                 u16* __restrict__ csr) {
    const int b = blockIdx.x;
    const int tid = threadIdx.x;
    const int r0 = b << 8;
    const int rcount = min(256, N_NODES - r0);
    __shared__ int pfx[ABLK + 1];
    __shared__ int cnts[ABLK];
    __shared__ int lbase[257];
    __shared__ u32 lcur[256];
    __shared__ __align__(16) u16 stage[STAGE_CAP];
    if (tid < ABLK) cnts[tid] = bcnt[tid * NB + b];
    for (int j = tid; j <= rcount; j += 256) lbase[j] = offsets[r0 + j] - offsets[r0];
    if (tid < 256) lcur[tid] = 0;
    __syncthreads();
    if (tid == 0) {
        int s = 0;
        for (int k = 0; k < ABLK; ++k) { pfx[k] = s; s += cnts[k]; }
        pfx[ABLK] = s;
    }
    __syncthreads();
    const int total = pfx[ABLK];
    const int L = min(lbase[rcount], STAGE_CAP);
    for (int j = tid; j < L; j += 256) stage[j] = (u16)ZERO_NODE;
    __syncthreads();
    for (int t = tid; t < total; t += 256) {
        int lo = 0, hi = ABLK;
        while (hi - lo > 1) { int mid = (lo + hi) >> 1; if (pfx[mid] <= t) lo = mid; else hi = mid; }
        u32 e = bucket[(size_t)lo * NB * BCAP + (size_t)b * BCAP + (t - pfx[lo])];
        int lr = (int)(e >> 16);
        u32 p = atomicAdd(&lcur[lr], 1u);
        int idx = lbase[lr] + (int)p;
        if (idx < STAGE_CAP) stage[idx] = (u16)(e & 0xffffu);
    }
    __syncthreads();
    // L is a multiple of PAD(16) -> whole segment is uint4-aligned in elements
    uint4* dst = (uint4*)(csr + offsets[r0]);
    const uint4* src = (const uint4*)stage;
    for (int j = tid; j < (L >> 3); j += 256) dst[j] = src[j];
}

// ---------------- build: mask bits + sxm = bf16(dis * masked x) --------------
__global__ void build_kernel(const void* __restrict__ mask,
                             const u32* __restrict__ flags,
                             const float* __restrict__ x,
                             const float* __restrict__ dis,
                             u32* __restrict__ bits,
                             u16* __restrict__ sxm, int n) {
    int i = blockIdx.x * blockDim.x + threadIdx.x;
    if (i >= n) return;
    u32 fl = *flags;
    int mv;
    if ((fl & 1u) == 0u) {
        mv = ((const int*)mask)[i];
    } else if (fl & 2u) {
        mv = (((const float*)mask)[i] != 0.0f) ? 1 : 0;
    } else {
        mv = ((const unsigned char*)mask)[i];
    }
    bool pred = (mv != 0);
    u64 b = __ballot(pred);
    int lane = threadIdx.x & 63;
    if (lane == 0)  bits[i >> 5] = (u32)b;
    if (lane == 32) bits[i >> 5] = (u32)(b >> 32);
    sxm[i] = pred ? bf16_rne(dis[i >> 7] * x[i]) : (u16)0;
}

// ---------------- one propagation step ---------------------------------------
// Branch-free: rows padded to multiple of 16 with ZERO_NODE (zeroed row).
// 16-edge body: 4 independent gathers/lane in flight, unroll 2 -> 8.
template <bool FINAL>
__global__ void __launch_bounds__(256) prop_kernel(const int* __restrict__ offsets,
                                                   const u16* __restrict__ csr,
                                                   const u16* __restrict__ cur,
                                                   const u32* __restrict__ bits,
                                                   const float* __restrict__ dis,
                                                   const u16* __restrict__ sxm,
                                                   const float* __restrict__ x,
                                                   void* __restrict__ nxtp) {
    const int tid = threadIdx.x;
    const int wid = tid >> 6, lane = tid & 63;
    const int node = blockIdx.x * 4 + wid;
    if (node >= N_NODES) return;
    const int fl = lane & 15, eg = lane >> 4;
    const int s = offsets[node], e = offsets[node + 1];

    float a0 = 0, a1 = 0, a2 = 0, a3 = 0, a4 = 0, a5 = 0, a6 = 0, a7 = 0;
#define ACC(r) \
    a0 += __uint_as_float((r).x << 16); \
    a1 += __uint_as_float((r).x & 0xffff0000u); \
    a2 += __uint_as_float((r).y << 16); \
    a3 += __uint_as_float((r).y & 0xffff0000u); \
    a4 += __uint_as_float((r).z << 16); \
    a5 += __uint_as_float((r).z & 0xffff0000u); \
    a6 += __uint_as_float((r).w << 16); \
    a7 += __uint_as_float((r).w & 0xffff0000u);

    #pragma unroll 2
    for (int base = s; base < e; base += 16) {
        const int c0 = (int)csr[base + eg];
        const int c1 = (int)csr[base + 4 + eg];
        const int c2 = (int)csr[base + 8 + eg];
        const int c3 = (int)csr[base + 12 + eg];
        const uint4 r0 = *((const uint4*)(cur + (size_t)c0 * D_FEAT) + fl);
        const uint4 r1 = *((const uint4*)(cur + (size_t)c1 * D_FEAT) + fl);
        const uint4 r2 = *((const uint4*)(cur + (size_t)c2 * D_FEAT) + fl);
        const uint4 r3 = *((const uint4*)(cur + (size_t)c3 * D_FEAT) + fl);
        ACC(r0); ACC(r1); ACC(r2); ACC(r3);
    }
#undef ACC
    a0 += __shfl_xor(a0, 16); a0 += __shfl_xor(a0, 32);
    a1 += __shfl_xor(a1, 16); a1 += __shfl_xor(a1, 32);
    a2 += __shfl_xor(a2, 16); a2 += __shfl_xor(a2, 32);
    a3 += __shfl_xor(a3, 16); a3 += __shfl_xor(a3, 32);
    a4 += __shfl_xor(a4, 16); a4 += __shfl_xor(a4, 32);
    a5 += __shfl_xor(a5, 16); a5 += __shfl_xor(a5, 32);
    a6 += __shfl_xor(a6, 16); a6 += __shfl_xor(a6, 32);
    a7 += __shfl_xor(a7, 16); a7 += __shfl_xor(a7, 32);

    if (eg == 0) {
        const int fbase = node * D_FEAT + fl * 8;
        const u32 w = bits[node * 4 + (fl >> 2)];
        const u32 mb = (w >> ((fl & 3) * 8)) & 0xffu;
        const float dr = dis[node];
        if (FINAL) {
            const float4 x0 = *(const float4*)(x + fbase);
            const float4 x1 = *(const float4*)(x + fbase + 4);
            float* outp = (float*)nxtp;
            float4 o0, o1;
            o0.x = (mb & 0x01u) ? x0.x : dr * a0;
            o0.y = (mb & 0x02u) ? x0.y : dr * a1;
            o0.z = (mb & 0x04u) ? x0.z : dr * a2;
            o0.w = (mb & 0x08u) ? x0.w : dr * a3;
            o1.x = (mb & 0x10u) ? x1.x : dr * a4;
            o1.y = (mb & 0x20u) ? x1.y : dr * a5;
            o1.z = (mb & 0x40u) ? x1.z : dr * a6;
            o1.w = (mb & 0x80u) ? x1.w : dr * a7;
            *(float4*)(outp + fbase) = o0;
            *(float4*)(outp + fbase + 4) = o1;
        } else {
            const float d2 = dr * dr;
            const uint4 sv = *(const uint4*)(sxm + fbase);
            u16 t0 = (mb & 0x01u) ? (u16)(sv.x)       : bf16_rne(d2 * a0);
            u16 t1 = (mb & 0x02u) ? (u16)(sv.x >> 16) : bf16_rne(d2 * a1);
            u16 t2 = (mb & 0x04u) ? (u16)(sv.y)       : bf16_rne(d2 * a2);
            u16 t3 = (mb & 0x08u) ? (u16)(sv.y >> 16) : bf16_rne(d2 * a3);
            u16 t4 = (mb & 0x10u) ? (u16)(sv.z)       : bf16_rne(d2 * a4);
            u16 t5 = (mb & 0x20u) ? (u16)(sv.z >> 16) : bf16_rne(d2 * a5);
            u16 t6 = (mb & 0x40u) ? (u16)(sv.w)       : bf16_rne(d2 * a6);
            u16 t7 = (mb & 0x80u) ? (u16)(sv.w >> 16) : bf16_rne(d2 * a7);
            uint4 st;
            st.x = (u32)t0 | ((u32)t1 << 16);
            st.y = (u32)t2 | ((u32)t3 << 16);
            st.z = (u32)t4 | ((u32)t5 << 16);
            st.w = (u32)t6 | ((u32)t7 << 16);
            *(uint4*)(((u16*)nxtp) + fbase) = st;
        }
    }
}

extern "C" void kernel_launch(void* const* d_in, const int* in_sizes, int n_in,
                              void* d_out, int out_size, void* d_ws, size_t ws_size,
                              hipStream_t stream) {
    const float* x = (const float*)d_in[0];
    const int* edge = (const int*)d_in[1];
    const void* mask = d_in[2];
    const int* row = edge;             // edge_index[0]
    const int* col = edge + N_EDGES;   // edge_index[1]
    float* out = (float*)d_out;

    char* ws = (char*)d_ws;
    size_t off = 0;
    auto alloc = [&](size_t bytes) -> void* {
        void* p = ws + off;
        off += (bytes + 255) & ~(size_t)255;
        return p;
    };
    const size_t state_elems = (size_t)(N_NODES + 1) * D_FEAT;  // +1 zero row
    int*   offsets = (int*)alloc((size_t)(N_NODES + 1) * 4);
    int*   cnt_p   = (int*)alloc((size_t)N_NODES * 4);
    float* dis     = (float*)alloc((size_t)N_NODES * 4);
    u32*   flags   = (u32*)alloc(256);
    u32*   bits    = (u32*)alloc((size_t)N_NODES * D_FEAT / 8);
    u32*   pA      = (u32*)alloc((size_t)HNB * (N_NODES / 2) * 4);    // 12.8 MB
    u32*   bucket  = (u32*)alloc((size_t)ABLK * NB * BCAP * 4);       // 19.3 MB
    int*   bcnt    = (int*)alloc((size_t)ABLK * NB * 4);
    u16*   csr     = (u16*)alloc((size_t)CSR_MAX * 2);
    u16*   sxm     = (u16*)alloc(state_elems * 2);
    u16*   stA     = (u16*)alloc(state_elems * 2);
    u16*   stB     = (u16*)alloc(state_elems * 2);

    (void)hipMemsetAsync(flags, 0, 4, stream);
    (void)hipMemsetAsync(sxm + (size_t)N_NODES * D_FEAT, 0, D_FEAT * 2, stream);
    (void)hipMemsetAsync(stA + (size_t)N_NODES * D_FEAT, 0, D_FEAT * 2, stream);
    (void)hipMemsetAsync(stB + (size_t)N_NODES * D_FEAT, 0, D_FEAT * 2, stream);

    const int total_feat = N_NODES * D_FEAT;
    const int mask_words = total_feat / 4;

    detect_kernel<<<1024, 256, 0, stream>>>((const u32*)mask, mask_words, flags);
    hist_kernel<<<2 * HNB, 256, 0, stream>>>(col, pA, N_EDGES);
    reduce_dis_kernel<<<(N_NODES / 2 + 255) / 256, 256, 0, stream>>>(pA, dis);
    bucketA_kernel<<<ABLK, 256, 0, stream>>>(row, col, bucket, bcnt);
    b1_kernel<<<NB, 256, 0, stream>>>(bucket, bcnt, cnt_p);
    scan_kernel<<<1, 1024, 0, stream>>>(cnt_p, offsets, N_NODES);
    build_kernel<<<total_feat / 256, 256, 0, stream>>>(mask, flags, x, dis, bits, sxm, total_feat);
    b2_kernel<<<NB, 256, 0, stream>>>(bucket, bcnt, offsets, csr);

    const int prop_blocks = (N_NODES + 3) / 4;
    const u16* src = sxm;  // s0 = dis * (mask ? x : 0) == sxm exactly
    for (int it = 0; it < NUM_ITERS; ++it) {
        if (it < NUM_ITERS - 1) {
            u16* dst = (it & 1) ? stB : stA;
            prop_kernel<false><<<prop_blocks, 256, 0, stream>>>(offsets, csr, src, bits, dis, sxm, x, dst);
            src = dst;
        } else {
            prop_kernel<true><<<prop_blocks, 256, 0, stream>>>(offsets, csr, src, bits, dis, sxm, x, out);
        }
    }
}